// Round 2
// baseline (261.932 us; speedup 1.0000x reference)
//
#include <hip/hip_runtime.h>
#include <hip/hip_bf16.h>

// MHA: B=4 S=1024 D=1024 H=16 depth=64. fp32 in/out; bf16 MFMA internally.

typedef __bf16 bf16x8 __attribute__((ext_vector_type(8)));
typedef __bf16 bf16x4 __attribute__((ext_vector_type(4)));
typedef float  f32x4  __attribute__((ext_vector_type(4)));
typedef float  f32x16 __attribute__((ext_vector_type(16)));

typedef const __attribute__((address_space(1))) void* gptr_t;
typedef __attribute__((address_space(3))) void* lptr_t;

#define MFMA16(a, b, c) __builtin_amdgcn_mfma_f32_16x16x32_bf16((a), (b), (c), 0, 0, 0)
#define MFMA32(a, b, c) __builtin_amdgcn_mfma_f32_32x32x16_bf16((a), (b), (c), 0, 0, 0)

__device__ __forceinline__ void gload_lds16(const void* g, void* l) {
  __builtin_amdgcn_global_load_lds((gptr_t)g, (lptr_t)l, 16, 0, 0);
}

__device__ __forceinline__ unsigned pack2(float a, float b) {
  union { __bf16 h[2]; unsigned u; } x;
  x.h[0] = (__bf16)a; x.h[1] = (__bf16)b; return x.u;
}

__device__ __forceinline__ bf16x8 mkfrag(unsigned a, unsigned b, unsigned c, unsigned d) {
  union { unsigned w[4]; bf16x8 v; } x;
  x.w[0] = a; x.w[1] = b; x.w[2] = c; x.w[3] = d; return x.v;
}

// ---------------- mask dtype detection + bit packing ----------------
// flag: 0 = int32, 1 = uint8/bool, 2 = float32
__global__ void detect_mask(const unsigned char* m, int* flag) {
  __shared__ int s1[4], s23[4];
  int tid = threadIdx.x;  // 256 threads, 16 B each = first 4096 B
  uint4 v = ((const uint4*)m)[tid];
  unsigned x0 = v.x, x1 = v.y, x2 = v.z, x3 = v.w;
  // byte offset %4==1 nonzero -> u8 data; bytes 2,3 nonzero -> f32 data
  unsigned c1  = (x0 & 0x0000ff00u) | (x1 & 0x0000ff00u) | (x2 & 0x0000ff00u) | (x3 & 0x0000ff00u);
  unsigned c23 = (x0 & 0xffff0000u) | (x1 & 0xffff0000u) | (x2 & 0xffff0000u) | (x3 & 0xffff0000u);
  unsigned long long b1 = __ballot(c1 != 0), b23 = __ballot(c23 != 0);
  if ((tid & 63) == 0) { s1[tid >> 6] = (b1 != 0); s23[tid >> 6] = (b23 != 0); }
  __syncthreads();
  if (tid == 0) {
    int a1 = s1[0] | s1[1] | s1[2] | s1[3];
    int a23 = s23[0] | s23[1] | s23[2] | s23[3];
    *flag = a1 ? 1 : (a23 ? 2 : 0);
  }
}

__global__ void pack_mask(const void* m, const int* flag, unsigned int* out) {
  size_t i = (size_t)blockIdx.x * 256 + threadIdx.x;  // element index, 4M total
  int f = *flag;
  bool v;
  if (f == 1)      v = ((const unsigned char*)m)[i] != 0;
  else if (f == 2) v = ((const float*)m)[i] != 0.0f;
  else             v = ((const int*)m)[i] != 0;
  unsigned long long bal = __ballot(v);
  int lane = threadIdx.x & 63;
  if ((lane & 31) == 0) out[i >> 5] = (unsigned int)(bal >> (lane & 32));
}

// ---------------- fp32 -> bf16 converts (vectorized) ----------------
__global__ void cvt3(const float* a, const float* b, const float* c,
                     __bf16* oa, __bf16* ob, __bf16* oc) {
  int bid = blockIdx.x;
  int which = bid >> 12, sub = bid & 4095;
  const float* in = which == 0 ? a : which == 1 ? b : c;
  __bf16* out = which == 0 ? oa : which == 1 ? ob : oc;
  size_t i = (size_t)sub * 256 + threadIdx.x;
  float4 v = ((const float4*)in)[i];
  bf16x4 o; o[0] = (__bf16)v.x; o[1] = (__bf16)v.y; o[2] = (__bf16)v.z; o[3] = (__bf16)v.w;
  ((bf16x4*)out)[i] = o;
}

__global__ void cvt4(const float* a, const float* b, const float* c, const float* d,
                     __bf16* oa, __bf16* ob, __bf16* oc, __bf16* od) {
  int bid = blockIdx.x;
  int which = bid >> 10, sub = bid & 1023;
  const float* in = which == 0 ? a : which == 1 ? b : which == 2 ? c : d;
  __bf16* out = which == 0 ? oa : which == 1 ? ob : which == 2 ? oc : od;
  size_t i = (size_t)sub * 256 + threadIdx.x;
  float4 v = ((const float4*)in)[i];
  bf16x4 o; o[0] = (__bf16)v.x; o[1] = (__bf16)v.y; o[2] = (__bf16)v.z; o[3] = (__bf16)v.w;
  ((bf16x4*)out)[i] = o;
}

// ---------------- fused QKV projection GEMM ----------------
__global__ __launch_bounds__(256, 2)
void gemm_qkv(const __bf16* qb, const __bf16* kb, const __bf16* vb,
              const __bf16* wq, const __bf16* wk, const __bf16* wv,
              const float* bq, const float* bk, const float* bv,
              __bf16* Qp, __bf16* Kp, __bf16* Vt) {
  __shared__ __bf16 As[128 * 64];
  __shared__ __bf16 Bs[128 * 64];
  const int bm = blockIdx.x;
  const int bnall = blockIdx.y;
  const int which = bnall >> 3;
  const int bn = bnall & 7;
  const __bf16* A = which == 0 ? qb : which == 1 ? kb : vb;
  const __bf16* W = which == 0 ? wq : which == 1 ? wk : wv;
  const float* bias = which == 0 ? bq : which == 1 ? bk : bv;

  const int tid = threadIdx.x, wave = tid >> 6, lane = tid & 63;
  const int wr = wave >> 1, wc = wave & 1;
  const int rl = lane >> 3, c8 = lane & 7;
  f32x4 acc[4][4] = {};

  for (int kt = 0; kt < 16; ++kt) {
    __syncthreads();
#pragma unroll
    for (int i = 0; i < 4; ++i) {
      int row = wave * 32 + i * 8 + rl;
      int sw = (c8 ^ (row & 7)) << 3;
      gload_lds16(A + (size_t)(bm * 128 + row) * 1024 + kt * 64 + sw, As + (wave * 32 + i * 8) * 64);
      gload_lds16(W + (size_t)(bn * 128 + row) * 1024 + kt * 64 + sw, Bs + (wave * 32 + i * 8) * 64);
    }
    __syncthreads();
#pragma unroll
    for (int k32 = 0; k32 < 2; ++k32) {
      bf16x8 af[4], bfr[4];
#pragma unroll
      for (int mi = 0; mi < 4; ++mi) {
        int row = wr * 64 + mi * 16 + (lane & 15);
        af[mi] = *(const bf16x8*)(As + row * 64 + (((k32 * 4 + (lane >> 4)) ^ (row & 7)) << 3));
      }
#pragma unroll
      for (int ni = 0; ni < 4; ++ni) {
        int row = wc * 64 + ni * 16 + (lane & 15);
        bfr[ni] = *(const bf16x8*)(Bs + row * 64 + (((k32 * 4 + (lane >> 4)) ^ (row & 7)) << 3));
      }
#pragma unroll
      for (int mi = 0; mi < 4; ++mi)
#pragma unroll
        for (int ni = 0; ni < 4; ++ni)
          acc[mi][ni] = MFMA16(af[mi], bfr[ni], acc[mi][ni]);
    }
  }
  const int r0 = (lane >> 4) * 4, cl = lane & 15;
  __bf16* Onat = which == 0 ? Qp : Kp;
#pragma unroll
  for (int ni = 0; ni < 4; ++ni) {
    int col = bn * 128 + wc * 64 + ni * 16 + cl;
    float bvv = bias[col];
#pragma unroll
    for (int mi = 0; mi < 4; ++mi) {
      int rowb = bm * 128 + wr * 64 + mi * 16 + r0;
      if (which < 2) {
#pragma unroll
        for (int r = 0; r < 4; ++r)
          Onat[(size_t)(rowb + r) * 1024 + col] = (__bf16)(acc[mi][ni][r] + bvv);
      } else {
        int bb = rowb >> 10, s0 = rowb & 1023, hh = col >> 6, d = col & 63;
        bf16x4 ov;
#pragma unroll
        for (int r = 0; r < 4; ++r) ov[r] = (__bf16)(acc[mi][ni][r] + bvv);
        *(bf16x4*)(Vt + (((size_t)(bb * 16 + hh) * 64 + d) << 10) + s0) = ov;
      }
    }
  }
}

// ---------------- output projection GEMM (fp32 out) ----------------
__global__ __launch_bounds__(256, 2)
void gemm_fc(const __bf16* A, const __bf16* W, const float* bias, float* C) {
  __shared__ __bf16 As[128 * 64];
  __shared__ __bf16 Bs[128 * 64];
  const int bm = blockIdx.x, bn = blockIdx.y;
  const int tid = threadIdx.x, wave = tid >> 6, lane = tid & 63;
  const int wr = wave >> 1, wc = wave & 1;
  const int rl = lane >> 3, c8 = lane & 7;
  f32x4 acc[4][4] = {};

  for (int kt = 0; kt < 16; ++kt) {
    __syncthreads();
#pragma unroll
    for (int i = 0; i < 4; ++i) {
      int row = wave * 32 + i * 8 + rl;
      int sw = (c8 ^ (row & 7)) << 3;
      gload_lds16(A + (size_t)(bm * 128 + row) * 1024 + kt * 64 + sw, As + (wave * 32 + i * 8) * 64);
      gload_lds16(W + (size_t)(bn * 128 + row) * 1024 + kt * 64 + sw, Bs + (wave * 32 + i * 8) * 64);
    }
    __syncthreads();
#pragma unroll
    for (int k32 = 0; k32 < 2; ++k32) {
      bf16x8 af[4], bfr[4];
#pragma unroll
      for (int mi = 0; mi < 4; ++mi) {
        int row = wr * 64 + mi * 16 + (lane & 15);
        af[mi] = *(const bf16x8*)(As + row * 64 + (((k32 * 4 + (lane >> 4)) ^ (row & 7)) << 3));
      }
#pragma unroll
      for (int ni = 0; ni < 4; ++ni) {
        int row = wc * 64 + ni * 16 + (lane & 15);
        bfr[ni] = *(const bf16x8*)(Bs + row * 64 + (((k32 * 4 + (lane >> 4)) ^ (row & 7)) << 3));
      }
#pragma unroll
      for (int mi = 0; mi < 4; ++mi)
#pragma unroll
        for (int ni = 0; ni < 4; ++ni)
          acc[mi][ni] = MFMA16(af[mi], bfr[ni], acc[mi][ni]);
    }
  }
  const int r0 = (lane >> 4) * 4, cl = lane & 15;
#pragma unroll
  for (int ni = 0; ni < 4; ++ni) {
    int col = bn * 128 + wc * 64 + ni * 16 + cl;
    float bvv = bias[col];
#pragma unroll
    for (int mi = 0; mi < 4; ++mi) {
      int rowb = bm * 128 + wr * 64 + mi * 16 + r0;
#pragma unroll
      for (int r = 0; r < 4; ++r)
        C[(size_t)(rowb + r) * 1024 + col] = acc[mi][ni][r] + bvv;
    }
  }
}

// ---------------- fused attention, 32x32 swapped-QK^T, in-register P ----------------
// Block: (b,h,128 q-rows), 4 waves, 32 q-rows/wave. No LDS, no barriers.
// QK^T computed swapped (A=K, B=Q) so S^T: col=q=lane&31, row=k=crow(r,hi).
// P packed to bf16 words; hi/lo half-wave block exchange via shfl_xor(32);
// PV A-frags assembled in-register (A layout: lane holds P[q=lane&31][8k at hi*8]).
__global__ __launch_bounds__(256)
void attn32(const __bf16* __restrict__ Qp, const __bf16* __restrict__ Kp,
            const __bf16* __restrict__ Vt, const unsigned long long* __restrict__ mp64,
            __bf16* __restrict__ O) {
  const int tid = threadIdx.x, wave = tid >> 6, lane = tid & 63;
  const int lo5 = lane & 31, hi = lane >> 5;
  const int bx = blockIdx.x;
  const int qt = bx & 7, h = (bx >> 3) & 15, b = bx >> 7;
  const int qrow = qt * 128 + wave * 32 + lo5;
  const float SC = 0.18033688011112042f;  // (1/8) * log2(e)

  // Q fragments: Q[qrow][d = 16m + hi*8 + j]
  bf16x8 qf[4];
  const __bf16* qb = Qp + ((size_t)(b * 1024 + qrow)) * 1024 + h * 64 + hi * 8;
#pragma unroll
  for (int m = 0; m < 4; ++m) qf[m] = *(const bf16x8*)(qb + m * 16);

  f32x16 oacc0 = {}, oacc1 = {};
  float dsum = 0.0f;
  const unsigned long long* mrow = mp64 + ((size_t)(b * 1024 + qrow)) * 16;
  const __bf16* vrow = Vt + ((size_t)((b * 16 + h) * 64 + lo5)) * 1024;

  for (int kt = 0; kt < 16; ++kt) {
    unsigned long long mw = mrow[kt];
    const __bf16* kb = Kp + ((size_t)(b * 1024 + kt * 64 + lo5)) * 1024 + h * 64 + hi * 8;
    const __bf16* vb = vrow + kt * 64 + hi * 8;

    // ---- k-subtile t=0: k = kt*64 + 0..31 ----
    f32x16 s0 = {};
#pragma unroll
    for (int m = 0; m < 4; ++m)
      s0 = MFMA32(*(const bf16x8*)(kb + m * 16), qf[m], s0);
    float p0[16];
#pragma unroll
    for (int r = 0; r < 16; ++r) {
      int cr = (r & 3) + 8 * (r >> 2) + 4 * hi;
      float e = exp2f(s0[r] * SC);
      p0[r] = ((mw >> cr) & 1) ? 0.0f : e;
      dsum += p0[r];
    }
    unsigned own0[8], rcv0[8];
#pragma unroll
    for (int u = 0; u < 4; ++u) {
      own0[2 * u]     = pack2(p0[4 * u],     p0[4 * u + 1]);
      own0[2 * u + 1] = pack2(p0[4 * u + 2], p0[4 * u + 3]);
    }
#pragma unroll
    for (int i = 0; i < 8; ++i) rcv0[i] = (unsigned)__shfl_xor((int)own0[i], 32, 64);
#pragma unroll
    for (int s = 0; s < 2; ++s) {
      const int ue2 = 4 * s, uo2 = 4 * s + 2;
      unsigned fw0 = hi ? rcv0[uo2 + 0] : own0[ue2 + 0];
      unsigned fw1 = hi ? rcv0[uo2 + 1] : own0[ue2 + 1];
      unsigned fw2 = hi ? own0[uo2 + 0] : rcv0[ue2 + 0];
      unsigned fw3 = hi ? own0[uo2 + 1] : rcv0[ue2 + 1];
      bf16x8 pa = mkfrag(fw0, fw1, fw2, fw3);
      bf16x8 vf0 = *(const bf16x8*)(vb + s * 16);
      bf16x8 vf1 = *(const bf16x8*)(vb + s * 16 + 32 * 1024);
      oacc0 = MFMA32(pa, vf0, oacc0);
      oacc1 = MFMA32(pa, vf1, oacc1);
    }

    // ---- k-subtile t=1: k = kt*64 + 32..63 ----
    f32x16 s1 = {};
#pragma unroll
    for (int m = 0; m < 4; ++m)
      s1 = MFMA32(*(const bf16x8*)(kb + 32 * 1024 + m * 16), qf[m], s1);
    float p1[16];
#pragma unroll
    for (int r = 0; r < 16; ++r) {
      int cr = (r & 3) + 8 * (r >> 2) + 4 * hi;
      float e = exp2f(s1[r] * SC);
      p1[r] = ((mw >> (32 + cr)) & 1) ? 0.0f : e;
      dsum += p1[r];
    }
    unsigned own1[8], rcv1[8];
#pragma unroll
    for (int u = 0; u < 4; ++u) {
      own1[2 * u]     = pack2(p1[4 * u],     p1[4 * u + 1]);
      own1[2 * u + 1] = pack2(p1[4 * u + 2], p1[4 * u + 3]);
    }
#pragma unroll
    for (int i = 0; i < 8; ++i) rcv1[i] = (unsigned)__shfl_xor((int)own1[i], 32, 64);
#pragma unroll
    for (int s = 0; s < 2; ++s) {
      const int ue2 = 4 * s, uo2 = 4 * s + 2;
      unsigned fw0 = hi ? rcv1[uo2 + 0] : own1[ue2 + 0];
      unsigned fw1 = hi ? rcv1[uo2 + 1] : own1[ue2 + 1];
      unsigned fw2 = hi ? own1[uo2 + 0] : rcv1[ue2 + 0];
      unsigned fw3 = hi ? own1[uo2 + 1] : rcv1[ue2 + 1];
      bf16x8 pa = mkfrag(fw0, fw1, fw2, fw3);
      bf16x8 vf0 = *(const bf16x8*)(vb + (s + 2) * 16);
      bf16x8 vf1 = *(const bf16x8*)(vb + (s + 2) * 16 + 32 * 1024);
      oacc0 = MFMA32(pa, vf0, oacc0);
      oacc1 = MFMA32(pa, vf1, oacc1);
    }
  }

  // row-sum across the hi/lo halves (each k counted once per pair)
  dsum += __shfl_xor(dsum, 32, 64);
  float inv = 1.0f / dsum;

  const size_t orow0 = (size_t)(b * 1024 + qt * 128 + wave * 32);
#pragma unroll
  for (int r = 0; r < 16; ++r) {
    int cr = (r & 3) + 8 * (r >> 2) + 4 * hi;
    float iv = __shfl(inv, cr, 64);  // inv lives at lane (lane&31)==q-local
    __bf16* op = O + (orow0 + cr) * 1024 + h * 64 + lo5;
    op[0]  = (__bf16)(oacc0[r] * iv);
    op[32] = (__bf16)(oacc1[r] * iv);
  }
}

// ---------------- launch ----------------
extern "C" void kernel_launch(void* const* d_in, const int* in_sizes, int n_in,
                              void* d_out, int out_size, void* d_ws, size_t ws_size,
                              hipStream_t stream) {
  const float* query = (const float*)d_in[0];
  const float* key   = (const float*)d_in[1];
  const float* value = (const float*)d_in[2];
  const void*  mask  = d_in[3];
  const float* wq_w  = (const float*)d_in[4];
  const float* wq_b  = (const float*)d_in[5];
  const float* wk_w  = (const float*)d_in[6];
  const float* wk_b  = (const float*)d_in[7];
  const float* wv_w  = (const float*)d_in[8];
  const float* wv_b  = (const float*)d_in[9];
  const float* fc_w  = (const float*)d_in[10];
  const float* fc_b  = (const float*)d_in[11];

  char* ws = (char*)d_ws;
  __bf16* qb  = (__bf16*)ws;
  __bf16* kb  = qb  + 4194304;
  __bf16* vb  = kb  + 4194304;
  __bf16* wqb = vb  + 4194304;
  __bf16* wkb = wqb + 1048576;
  __bf16* wvb = wkb + 1048576;
  __bf16* fcb = wvb + 1048576;
  __bf16* Qp  = fcb + 1048576;
  __bf16* Kp  = Qp  + 4194304;
  __bf16* Vt  = Kp  + 4194304;        // V proj, per-head transposed [B,H,64,S]
  __bf16* Ob  = Vt  + 4194304;
  unsigned int* mpk = (unsigned int*)(Ob + 4194304);
  int* flag = (int*)(mpk + 131072);

  detect_mask<<<1, 256, 0, stream>>>((const unsigned char*)mask, flag);
  pack_mask<<<16384, 256, 0, stream>>>(mask, flag, mpk);
  cvt3<<<12288, 256, 0, stream>>>(query, key, value, qb, kb, vb);
  cvt4<<<4096, 256, 0, stream>>>(wq_w, wk_w, wv_w, fc_w, wqb, wkb, wvb, fcb);
  dim3 g1(32, 24);
  gemm_qkv<<<g1, 256, 0, stream>>>(qb, kb, vb, wqb, wkb, wvb, wq_b, wk_b, wv_b, Qp, Kp, Vt);
  attn32<<<512, 256, 0, stream>>>(Qp, Kp, Vt, (const unsigned long long*)mpk, Ob);
  dim3 g2(32, 8);
  gemm_fc<<<g2, 256, 0, stream>>>(Ob, fcb, fc_b, (float*)d_out);
}

// Round 3
// 248.339 us; speedup vs baseline: 1.0547x; 1.0547x over previous
//
#include <hip/hip_runtime.h>
#include <hip/hip_bf16.h>

// MHA: B=4 S=1024 D=1024 H=16 depth=64. fp32 in/out; bf16 MFMA internally.

typedef __bf16 bf16x8 __attribute__((ext_vector_type(8)));
typedef __bf16 bf16x4 __attribute__((ext_vector_type(4)));
typedef float  f32x4  __attribute__((ext_vector_type(4)));
typedef float  f32x16 __attribute__((ext_vector_type(16)));

typedef const __attribute__((address_space(1))) void* gptr_t;
typedef __attribute__((address_space(3))) void* lptr_t;

#define MFMA16(a, b, c) __builtin_amdgcn_mfma_f32_16x16x32_bf16((a), (b), (c), 0, 0, 0)
#define MFMA32(a, b, c) __builtin_amdgcn_mfma_f32_32x32x16_bf16((a), (b), (c), 0, 0, 0)

__device__ __forceinline__ void gload_lds16(const void* g, void* l) {
  __builtin_amdgcn_global_load_lds((gptr_t)g, (lptr_t)l, 16, 0, 0);
}

__device__ __forceinline__ unsigned pack2(float a, float b) {
  union { __bf16 h[2]; unsigned u; } x;
  x.h[0] = (__bf16)a; x.h[1] = (__bf16)b; return x.u;
}

__device__ __forceinline__ bf16x8 mkfrag(unsigned a, unsigned b, unsigned c, unsigned d) {
  union { unsigned w[4]; bf16x8 v; } x;
  x.w[0] = a; x.w[1] = b; x.w[2] = c; x.w[3] = d; return x.v;
}

// ---------------- mask dtype detection + bit packing ----------------
__global__ void detect_mask(const unsigned char* m, int* flag) {
  __shared__ int s1[4], s23[4];
  int tid = threadIdx.x;
  uint4 v = ((const uint4*)m)[tid];
  unsigned x0 = v.x, x1 = v.y, x2 = v.z, x3 = v.w;
  unsigned c1  = (x0 & 0x0000ff00u) | (x1 & 0x0000ff00u) | (x2 & 0x0000ff00u) | (x3 & 0x0000ff00u);
  unsigned c23 = (x0 & 0xffff0000u) | (x1 & 0xffff0000u) | (x2 & 0xffff0000u) | (x3 & 0xffff0000u);
  unsigned long long b1 = __ballot(c1 != 0), b23 = __ballot(c23 != 0);
  if ((tid & 63) == 0) { s1[tid >> 6] = (b1 != 0); s23[tid >> 6] = (b23 != 0); }
  __syncthreads();
  if (tid == 0) {
    int a1 = s1[0] | s1[1] | s1[2] | s1[3];
    int a23 = s23[0] | s23[1] | s23[2] | s23[3];
    *flag = a1 ? 1 : (a23 ? 2 : 0);
  }
}

__global__ void pack_mask(const void* m, const int* flag, unsigned int* out) {
  size_t i = (size_t)blockIdx.x * 256 + threadIdx.x;
  int f = *flag;
  bool v;
  if (f == 1)      v = ((const unsigned char*)m)[i] != 0;
  else if (f == 2) v = ((const float*)m)[i] != 0.0f;
  else             v = ((const int*)m)[i] != 0;
  unsigned long long bal = __ballot(v);
  int lane = threadIdx.x & 63;
  if ((lane & 31) == 0) out[i >> 5] = (unsigned int)(bal >> (lane & 32));
}

// ---------------- fp32 -> bf16 convert, all 7 tensors in one dispatch ----------------
__global__ void cvt_all(const float* q, const float* k, const float* v,
                        const float* w0, const float* w1, const float* w2, const float* w3,
                        __bf16* oq, __bf16* ok, __bf16* ov,
                        __bf16* o0, __bf16* o1, __bf16* o2, __bf16* o3) {
  int bid = blockIdx.x;
  const float* in; __bf16* out; int sub;
  if (bid < 12288) {
    int w = bid >> 12; sub = bid & 4095;
    in = w == 0 ? q : w == 1 ? k : v;
    out = w == 0 ? oq : w == 1 ? ok : ov;
  } else {
    int w = (bid - 12288) >> 10; sub = (bid - 12288) & 1023;
    in = w == 0 ? w0 : w == 1 ? w1 : w == 2 ? w2 : w3;
    out = w == 0 ? o0 : w == 1 ? o1 : w == 2 ? o2 : o3;
  }
  size_t i = (size_t)sub * 256 + threadIdx.x;
  float4 vv = ((const float4*)in)[i];
  bf16x4 o; o[0] = (__bf16)vv.x; o[1] = (__bf16)vv.y; o[2] = (__bf16)vv.z; o[3] = (__bf16)vv.w;
  ((bf16x4*)out)[i] = o;
}

// ---------------- fused QKV projection GEMM (2-phase dbuf) ----------------
__global__ __launch_bounds__(256, 2)
void gemm_qkv(const __bf16* __restrict__ qb, const __bf16* __restrict__ kb,
              const __bf16* __restrict__ vb,
              const __bf16* __restrict__ wq, const __bf16* __restrict__ wk,
              const __bf16* __restrict__ wv,
              const float* __restrict__ bq, const float* __restrict__ bk,
              const float* __restrict__ bv,
              __bf16* __restrict__ Qp, __bf16* __restrict__ Kp, __bf16* __restrict__ Vt) {
  __shared__ __bf16 As[2][128 * 64];
  __shared__ __bf16 Bs[2][128 * 64];
  const int bm = blockIdx.x;
  const int bnall = blockIdx.y;
  const int which = bnall >> 3;
  const int bn = bnall & 7;
  const __bf16* A = which == 0 ? qb : which == 1 ? kb : vb;
  const __bf16* W = which == 0 ? wq : which == 1 ? wk : wv;
  const float* bias = which == 0 ? bq : which == 1 ? bk : bv;

  const int tid = threadIdx.x, wave = tid >> 6, lane = tid & 63;
  const int wr = wave >> 1, wc = wave & 1;
  const int rl = lane >> 3, c8 = lane & 7;
  f32x4 acc[4][4] = {};

#define QKV_STAGE(bb, kt)                                                             \
  {                                                                                   \
    _Pragma("unroll")                                                                 \
    for (int i = 0; i < 4; ++i) {                                                     \
      int row = wave * 32 + i * 8 + rl;                                               \
      int sw = (c8 ^ (row & 7)) << 3;                                                 \
      gload_lds16(A + (size_t)(bm * 128 + row) * 1024 + (kt) * 64 + sw,               \
                  &As[bb][(wave * 32 + i * 8) * 64]);                                 \
      gload_lds16(W + (size_t)(bn * 128 + row) * 1024 + (kt) * 64 + sw,               \
                  &Bs[bb][(wave * 32 + i * 8) * 64]);                                 \
    }                                                                                 \
  }

  QKV_STAGE(0, 0);
  __syncthreads();
  int buf = 0;
  for (int kt = 0; kt < 16; ++kt) {
    if (kt < 15) QKV_STAGE(buf ^ 1, kt + 1);
#pragma unroll
    for (int k32 = 0; k32 < 2; ++k32) {
      bf16x8 af[4], bfr[4];
#pragma unroll
      for (int mi = 0; mi < 4; ++mi) {
        int row = wr * 64 + mi * 16 + (lane & 15);
        af[mi] = *(const bf16x8*)(&As[buf][row * 64 + (((k32 * 4 + (lane >> 4)) ^ (row & 7)) << 3)]);
      }
#pragma unroll
      for (int ni = 0; ni < 4; ++ni) {
        int row = wc * 64 + ni * 16 + (lane & 15);
        bfr[ni] = *(const bf16x8*)(&Bs[buf][row * 64 + (((k32 * 4 + (lane >> 4)) ^ (row & 7)) << 3)]);
      }
#pragma unroll
      for (int mi = 0; mi < 4; ++mi)
#pragma unroll
        for (int ni = 0; ni < 4; ++ni)
          acc[mi][ni] = MFMA16(af[mi], bfr[ni], acc[mi][ni]);
    }
    __syncthreads();
    buf ^= 1;
  }
  const int r0 = (lane >> 4) * 4, cl = lane & 15;
  __bf16* Onat = which == 0 ? Qp : Kp;
#pragma unroll
  for (int ni = 0; ni < 4; ++ni) {
    int col = bn * 128 + wc * 64 + ni * 16 + cl;
    float bvv = bias[col];
#pragma unroll
    for (int mi = 0; mi < 4; ++mi) {
      int rowb = bm * 128 + wr * 64 + mi * 16 + r0;
      if (which < 2) {
#pragma unroll
        for (int r = 0; r < 4; ++r)
          Onat[(size_t)(rowb + r) * 1024 + col] = (__bf16)(acc[mi][ni][r] + bvv);
      } else {
        int bb = rowb >> 10, s0 = rowb & 1023, hh = col >> 6, d = col & 63;
        bf16x4 ov;
#pragma unroll
        for (int r = 0; r < 4; ++r) ov[r] = (__bf16)(acc[mi][ni][r] + bvv);
        *(bf16x4*)(Vt + (((size_t)(bb * 16 + hh) * 64 + d) << 10) + s0) = ov;
      }
    }
  }
}

// ---------------- output projection GEMM (fp32 out, 2-phase dbuf) ----------------
__global__ __launch_bounds__(256, 2)
void gemm_fc(const __bf16* __restrict__ A, const __bf16* __restrict__ W,
             const float* __restrict__ bias, float* __restrict__ C) {
  __shared__ __bf16 As[2][128 * 64];
  __shared__ __bf16 Bs[2][128 * 64];
  const int bm = blockIdx.x, bn = blockIdx.y;
  const int tid = threadIdx.x, wave = tid >> 6, lane = tid & 63;
  const int wr = wave >> 1, wc = wave & 1;
  const int rl = lane >> 3, c8 = lane & 7;
  f32x4 acc[4][4] = {};

#define FC_STAGE(bb, kt)                                                              \
  {                                                                                   \
    _Pragma("unroll")                                                                 \
    for (int i = 0; i < 4; ++i) {                                                     \
      int row = wave * 32 + i * 8 + rl;                                               \
      int sw = (c8 ^ (row & 7)) << 3;                                                 \
      gload_lds16(A + (size_t)(bm * 128 + row) * 1024 + (kt) * 64 + sw,               \
                  &As[bb][(wave * 32 + i * 8) * 64]);                                 \
      gload_lds16(W + (size_t)(bn * 128 + row) * 1024 + (kt) * 64 + sw,               \
                  &Bs[bb][(wave * 32 + i * 8) * 64]);                                 \
    }                                                                                 \
  }

  FC_STAGE(0, 0);
  __syncthreads();
  int buf = 0;
  for (int kt = 0; kt < 16; ++kt) {
    if (kt < 15) FC_STAGE(buf ^ 1, kt + 1);
#pragma unroll
    for (int k32 = 0; k32 < 2; ++k32) {
      bf16x8 af[4], bfr[4];
#pragma unroll
      for (int mi = 0; mi < 4; ++mi) {
        int row = wr * 64 + mi * 16 + (lane & 15);
        af[mi] = *(const bf16x8*)(&As[buf][row * 64 + (((k32 * 4 + (lane >> 4)) ^ (row & 7)) << 3)]);
      }
#pragma unroll
      for (int ni = 0; ni < 4; ++ni) {
        int row = wc * 64 + ni * 16 + (lane & 15);
        bfr[ni] = *(const bf16x8*)(&Bs[buf][row * 64 + (((k32 * 4 + (lane >> 4)) ^ (row & 7)) << 3)]);
      }
#pragma unroll
      for (int mi = 0; mi < 4; ++mi)
#pragma unroll
        for (int ni = 0; ni < 4; ++ni)
          acc[mi][ni] = MFMA16(af[mi], bfr[ni], acc[mi][ni]);
    }
    __syncthreads();
    buf ^= 1;
  }
  const int r0 = (lane >> 4) * 4, cl = lane & 15;
#pragma unroll
  for (int ni = 0; ni < 4; ++ni) {
    int col = bn * 128 + wc * 64 + ni * 16 + cl;
    float bvv = bias[col];
#pragma unroll
    for (int mi = 0; mi < 4; ++mi) {
      int rowb = bm * 128 + wr * 64 + mi * 16 + r0;
#pragma unroll
      for (int r = 0; r < 4; ++r)
        C[(size_t)(rowb + r) * 1024 + col] = acc[mi][ni][r] + bvv;
    }
  }
}

// ---------------- fused attention: LDS-staged K/V + in-register P ----------------
// Block: (b,h,128 q-rows), 4 waves x 32 q-rows. K/V tiles (64 kv-rows) staged
// via global_load_lds with both-sides XOR swizzle, double-buffered 2-phase.
// Swapped QK^T (A=K,B=Q) -> S^T col=q=lane&31, row=k=crow(r,hi); P stays in
// registers; hi/lo half exchange via shfl_xor(32); PV B-operand = V^T from LDS.
__global__ __launch_bounds__(256)
void attn32(const __bf16* __restrict__ Qp, const __bf16* __restrict__ Kp,
            const __bf16* __restrict__ Vt, const unsigned long long* __restrict__ mp64,
            __bf16* __restrict__ O) {
  __shared__ __bf16 Ks[2][64 * 64];   // [kv-local][d] granule-swizzled by row&7
  __shared__ __bf16 Vs[2][64 * 64];   // [d][kv-local] granule-swizzled by row&7
  const int tid = threadIdx.x, wave = tid >> 6, lane = tid & 63;
  const int lo5 = lane & 31, hi = lane >> 5;
  const int bx = blockIdx.x;
  const int qt = bx & 7, h = (bx >> 3) & 15, b = bx >> 7;
  const int qrow = qt * 128 + wave * 32 + lo5;
  const float SC = 0.18033688011112042f;  // (1/8) * log2(e)

  // staging geometry: 256 threads x 16B = 32 rows/issue; 2 issues per 64-row tile
  const int srow = tid >> 3;           // local row within issue
  const int sgx = ((tid & 7) ^ (srow & 7)) << 3;  // pre-swizzled source granule

#define ATTN_STAGE(bb, kt)                                                            \
  {                                                                                   \
    _Pragma("unroll")                                                                 \
    for (int i = 0; i < 2; ++i) {                                                     \
      gload_lds16(Kp + (size_t)(b * 1024 + (kt) * 64 + i * 32 + srow) * 1024          \
                     + h * 64 + sgx,                                                  \
                  &Ks[bb][i * 2048 + wave * 512]);                                    \
      gload_lds16(Vt + (size_t)((b * 16 + h) * 64 + i * 32 + srow) * 1024             \
                     + (kt) * 64 + sgx,                                               \
                  &Vs[bb][i * 2048 + wave * 512]);                                    \
    }                                                                                 \
  }

  // Q fragments from global (one-time): Q[qrow][d = 16m + hi*8 + j]
  bf16x8 qf[4];
  const __bf16* qb = Qp + ((size_t)(b * 1024 + qrow)) * 1024 + h * 64 + hi * 8;
#pragma unroll
  for (int m = 0; m < 4; ++m) qf[m] = *(const bf16x8*)(qb + m * 16);

  f32x16 oacc0 = {}, oacc1 = {};
  float dsum = 0.0f;
  const unsigned long long* mrow = mp64 + ((size_t)(b * 1024 + qrow)) * 16;
  const int x = lo5 & 7;

  ATTN_STAGE(0, 0);
  __syncthreads();
  int buf = 0;
  for (int kt = 0; kt < 16; ++kt) {
    if (kt < 15) ATTN_STAGE(buf ^ 1, kt + 1);
    unsigned long long mw = mrow[kt];
#pragma unroll
    for (int sub = 0; sub < 2; ++sub) {
      // S^T subtile: rows k = kt*64 + sub*32 + crow, cols q
      f32x16 s = {};
#pragma unroll
      for (int m = 0; m < 4; ++m) {
        bf16x8 kf = *(const bf16x8*)(&Ks[buf][(sub * 32 + lo5) * 64 + (((2 * m + hi) ^ x) << 3)]);
        s = MFMA32(kf, qf[m], s);
      }
      float p[16];
#pragma unroll
      for (int r = 0; r < 16; ++r) {
        int cr = (r & 3) + 8 * (r >> 2) + 4 * hi;
        float e = exp2f(s[r] * SC);
        p[r] = ((mw >> (sub * 32 + cr)) & 1) ? 0.0f : e;
        dsum += p[r];
      }
      unsigned own[8], rcv[8];
#pragma unroll
      for (int u = 0; u < 4; ++u) {
        own[2 * u]     = pack2(p[4 * u],     p[4 * u + 1]);
        own[2 * u + 1] = pack2(p[4 * u + 2], p[4 * u + 3]);
      }
#pragma unroll
      for (int i = 0; i < 8; ++i) rcv[i] = (unsigned)__shfl_xor((int)own[i], 32, 64);
#pragma unroll
      for (int sf = 0; sf < 2; ++sf) {
        const int ue2 = 4 * sf, uo2 = 4 * sf + 2;
        unsigned fw0 = hi ? rcv[uo2 + 0] : own[ue2 + 0];
        unsigned fw1 = hi ? rcv[uo2 + 1] : own[ue2 + 1];
        unsigned fw2 = hi ? own[uo2 + 0] : rcv[ue2 + 0];
        unsigned fw3 = hi ? own[uo2 + 1] : rcv[ue2 + 1];
        bf16x8 pa = mkfrag(fw0, fw1, fw2, fw3);
        int g = ((sub * 4 + sf * 2 + hi) ^ x) << 3;  // k-granule, swizzled by row(d)&7
        bf16x8 vf0 = *(const bf16x8*)(&Vs[buf][lo5 * 64 + g]);
        bf16x8 vf1 = *(const bf16x8*)(&Vs[buf][(lo5 + 32) * 64 + g]);
        oacc0 = MFMA32(pa, vf0, oacc0);
        oacc1 = MFMA32(pa, vf1, oacc1);
      }
    }
    __syncthreads();
    buf ^= 1;
  }

  // row-sum across hi/lo halves
  dsum += __shfl_xor(dsum, 32, 64);
  float inv = 1.0f / dsum;

  const size_t orow0 = (size_t)(b * 1024 + qt * 128 + wave * 32);
#pragma unroll
  for (int r = 0; r < 16; ++r) {
    int cr = (r & 3) + 8 * (r >> 2) + 4 * hi;
    float iv = __shfl(inv, cr, 64);
    __bf16* op = O + (orow0 + cr) * 1024 + h * 64 + lo5;
    op[0]  = (__bf16)(oacc0[r] * iv);
    op[32] = (__bf16)(oacc1[r] * iv);
  }
}

// ---------------- launch ----------------
extern "C" void kernel_launch(void* const* d_in, const int* in_sizes, int n_in,
                              void* d_out, int out_size, void* d_ws, size_t ws_size,
                              hipStream_t stream) {
  const float* query = (const float*)d_in[0];
  const float* key   = (const float*)d_in[1];
  const float* value = (const float*)d_in[2];
  const void*  mask  = d_in[3];
  const float* wq_w  = (const float*)d_in[4];
  const float* wq_b  = (const float*)d_in[5];
  const float* wk_w  = (const float*)d_in[6];
  const float* wk_b  = (const float*)d_in[7];
  const float* wv_w  = (const float*)d_in[8];
  const float* wv_b  = (const float*)d_in[9];
  const float* fc_w  = (const float*)d_in[10];
  const float* fc_b  = (const float*)d_in[11];

  char* ws = (char*)d_ws;
  __bf16* qb  = (__bf16*)ws;
  __bf16* kb  = qb  + 4194304;
  __bf16* vb  = kb  + 4194304;
  __bf16* wqb = vb  + 4194304;
  __bf16* wkb = wqb + 1048576;
  __bf16* wvb = wkb + 1048576;
  __bf16* fcb = wvb + 1048576;
  __bf16* Qp  = fcb + 1048576;
  __bf16* Kp  = Qp  + 4194304;
  __bf16* Vt  = Kp  + 4194304;        // V proj, per-head transposed [B,H,64,S]
  __bf16* Ob  = Vt  + 4194304;
  unsigned int* mpk = (unsigned int*)(Ob + 4194304);
  int* flag = (int*)(mpk + 131072);

  detect_mask<<<1, 256, 0, stream>>>((const unsigned char*)mask, flag);
  pack_mask<<<16384, 256, 0, stream>>>(mask, flag, mpk);
  cvt_all<<<16384, 256, 0, stream>>>(query, key, value, wq_w, wk_w, wv_w, fc_w,
                                     qb, kb, vb, wqb, wkb, wvb, fcb);
  dim3 g1(32, 24);
  gemm_qkv<<<g1, 256, 0, stream>>>(qb, kb, vb, wqb, wkb, wvb, wq_b, wk_b, wv_b, Qp, Kp, Vt);
  attn32<<<512, 256, 0, stream>>>(Qp, Kp, Vt, (const unsigned long long*)mpk, Ob);
  dim3 g2(32, 8);
  gemm_fc<<<g2, 256, 0, stream>>>(Ob, fcb, fc_b, (float*)d_out);
}

// Round 4
// 236.572 us; speedup vs baseline: 1.1072x; 1.0497x over previous
//
#include <hip/hip_runtime.h>
#include <hip/hip_bf16.h>

// MHA: B=4 S=1024 D=1024 H=16 depth=64. fp32 in/out; bf16 MFMA internally.

typedef __bf16 bf16x8 __attribute__((ext_vector_type(8)));
typedef __bf16 bf16x4 __attribute__((ext_vector_type(4)));
typedef float  f32x4  __attribute__((ext_vector_type(4)));
typedef float  f32x16 __attribute__((ext_vector_type(16)));

typedef const __attribute__((address_space(1))) void* gptr_t;
typedef __attribute__((address_space(3))) void* lptr_t;

#define MFMA16(a, b, c) __builtin_amdgcn_mfma_f32_16x16x32_bf16((a), (b), (c), 0, 0, 0)
#define MFMA32(a, b, c) __builtin_amdgcn_mfma_f32_32x32x16_bf16((a), (b), (c), 0, 0, 0)

__device__ __forceinline__ void gload_lds16(const void* g, void* l) {
  __builtin_amdgcn_global_load_lds((gptr_t)g, (lptr_t)l, 16, 0, 0);
}

__device__ __forceinline__ unsigned pack2(float a, float b) {
  union { __bf16 h[2]; unsigned u; } x;
  x.h[0] = (__bf16)a; x.h[1] = (__bf16)b; return x.u;
}

__device__ __forceinline__ bf16x8 mkfrag(unsigned a, unsigned b, unsigned c, unsigned d) {
  union { unsigned w[4]; bf16x8 v; } x;
  x.w[0] = a; x.w[1] = b; x.w[2] = c; x.w[3] = d; return x.v;
}

// ---------------- mask dtype detection + bit packing ----------------
__global__ void detect_mask(const unsigned char* m, int* flag) {
  __shared__ int s1[4], s23[4];
  int tid = threadIdx.x;
  uint4 v = ((const uint4*)m)[tid];
  unsigned x0 = v.x, x1 = v.y, x2 = v.z, x3 = v.w;
  unsigned c1  = (x0 & 0x0000ff00u) | (x1 & 0x0000ff00u) | (x2 & 0x0000ff00u) | (x3 & 0x0000ff00u);
  unsigned c23 = (x0 & 0xffff0000u) | (x1 & 0xffff0000u) | (x2 & 0xffff0000u) | (x3 & 0xffff0000u);
  unsigned long long b1 = __ballot(c1 != 0), b23 = __ballot(c23 != 0);
  if ((tid & 63) == 0) { s1[tid >> 6] = (b1 != 0); s23[tid >> 6] = (b23 != 0); }
  __syncthreads();
  if (tid == 0) {
    int a1 = s1[0] | s1[1] | s1[2] | s1[3];
    int a23 = s23[0] | s23[1] | s23[2] | s23[3];
    *flag = a1 ? 1 : (a23 ? 2 : 0);
  }
}

__global__ void pack_mask(const void* m, const int* flag, unsigned int* out) {
  size_t i = (size_t)blockIdx.x * 256 + threadIdx.x;
  int f = *flag;
  bool v;
  if (f == 1)      v = ((const unsigned char*)m)[i] != 0;
  else if (f == 2) v = ((const float*)m)[i] != 0.0f;
  else             v = ((const int*)m)[i] != 0;
  unsigned long long bal = __ballot(v);
  int lane = threadIdx.x & 63;
  if ((lane & 31) == 0) out[i >> 5] = (unsigned int)(bal >> (lane & 32));
}

// ---------------- fp32 -> bf16 convert, all 7 tensors in one dispatch ----------------
__global__ void cvt_all(const float* q, const float* k, const float* v,
                        const float* w0, const float* w1, const float* w2, const float* w3,
                        __bf16* oq, __bf16* ok, __bf16* ov,
                        __bf16* o0, __bf16* o1, __bf16* o2, __bf16* o3) {
  int bid = blockIdx.x;
  const float* in; __bf16* out; int sub;
  if (bid < 12288) {
    int w = bid >> 12; sub = bid & 4095;
    in = w == 0 ? q : w == 1 ? k : v;
    out = w == 0 ? oq : w == 1 ? ok : ov;
  } else {
    int w = (bid - 12288) >> 10; sub = (bid - 12288) & 1023;
    in = w == 0 ? w0 : w == 1 ? w1 : w == 2 ? w2 : w3;
    out = w == 0 ? o0 : w == 1 ? o1 : w == 2 ? o2 : o3;
  }
  size_t i = (size_t)sub * 256 + threadIdx.x;
  float4 vv = ((const float4*)in)[i];
  bf16x4 o; o[0] = (__bf16)vv.x; o[1] = (__bf16)vv.y; o[2] = (__bf16)vv.z; o[3] = (__bf16)vv.w;
  ((bf16x4*)out)[i] = o;
}

// ---------------- fused QKV projection GEMM (2-phase dbuf) ----------------
// Q output pre-scaled by (1/sqrt(64))*log2(e) so attn uses exp2 directly.
__global__ __launch_bounds__(256, 2)
void gemm_qkv(const __bf16* __restrict__ qb, const __bf16* __restrict__ kb,
              const __bf16* __restrict__ vb,
              const __bf16* __restrict__ wq, const __bf16* __restrict__ wk,
              const __bf16* __restrict__ wv,
              const float* __restrict__ bq, const float* __restrict__ bk,
              const float* __restrict__ bv,
              __bf16* __restrict__ Qp, __bf16* __restrict__ Kp, __bf16* __restrict__ Vt) {
  __shared__ __bf16 As[2][128 * 64];
  __shared__ __bf16 Bs[2][128 * 64];
  const int bm = blockIdx.x;
  const int bnall = blockIdx.y;
  const int which = bnall >> 3;
  const int bn = bnall & 7;
  const __bf16* A = which == 0 ? qb : which == 1 ? kb : vb;
  const __bf16* W = which == 0 ? wq : which == 1 ? wk : wv;
  const float* bias = which == 0 ? bq : which == 1 ? bk : bv;

  const int tid = threadIdx.x, wave = tid >> 6, lane = tid & 63;
  const int wr = wave >> 1, wc = wave & 1;
  const int rl = lane >> 3, c8 = lane & 7;
  f32x4 acc[4][4] = {};

#define QKV_STAGE(bb, kt)                                                             \
  {                                                                                   \
    _Pragma("unroll")                                                                 \
    for (int i = 0; i < 4; ++i) {                                                     \
      int row = wave * 32 + i * 8 + rl;                                               \
      int sw = (c8 ^ (row & 7)) << 3;                                                 \
      gload_lds16(A + (size_t)(bm * 128 + row) * 1024 + (kt) * 64 + sw,               \
                  &As[bb][(wave * 32 + i * 8) * 64]);                                 \
      gload_lds16(W + (size_t)(bn * 128 + row) * 1024 + (kt) * 64 + sw,               \
                  &Bs[bb][(wave * 32 + i * 8) * 64]);                                 \
    }                                                                                 \
  }

  QKV_STAGE(0, 0);
  __syncthreads();
  int buf = 0;
  for (int kt = 0; kt < 16; ++kt) {
    if (kt < 15) QKV_STAGE(buf ^ 1, kt + 1);
#pragma unroll
    for (int k32 = 0; k32 < 2; ++k32) {
      bf16x8 af[4], bfr[4];
#pragma unroll
      for (int mi = 0; mi < 4; ++mi) {
        int row = wr * 64 + mi * 16 + (lane & 15);
        af[mi] = *(const bf16x8*)(&As[buf][row * 64 + (((k32 * 4 + (lane >> 4)) ^ (row & 7)) << 3)]);
      }
#pragma unroll
      for (int ni = 0; ni < 4; ++ni) {
        int row = wc * 64 + ni * 16 + (lane & 15);
        bfr[ni] = *(const bf16x8*)(&Bs[buf][row * 64 + (((k32 * 4 + (lane >> 4)) ^ (row & 7)) << 3)]);
      }
#pragma unroll
      for (int mi = 0; mi < 4; ++mi)
#pragma unroll
        for (int ni = 0; ni < 4; ++ni)
          acc[mi][ni] = MFMA16(af[mi], bfr[ni], acc[mi][ni]);
    }
    __syncthreads();
    buf ^= 1;
  }
  const int r0 = (lane >> 4) * 4, cl = lane & 15;
  const float osc = (which == 0) ? 0.18033688011112042f : 1.0f;  // fold 1/8*log2(e) into Q
  __bf16* Onat = which == 0 ? Qp : Kp;
#pragma unroll
  for (int ni = 0; ni < 4; ++ni) {
    int col = bn * 128 + wc * 64 + ni * 16 + cl;
    float bvv = bias[col];
#pragma unroll
    for (int mi = 0; mi < 4; ++mi) {
      int rowb = bm * 128 + wr * 64 + mi * 16 + r0;
      if (which < 2) {
#pragma unroll
        for (int r = 0; r < 4; ++r)
          Onat[(size_t)(rowb + r) * 1024 + col] = (__bf16)((acc[mi][ni][r] + bvv) * osc);
      } else {
        int bb = rowb >> 10, s0 = rowb & 1023, hh = col >> 6, d = col & 63;
        bf16x4 ov;
#pragma unroll
        for (int r = 0; r < 4; ++r) ov[r] = (__bf16)(acc[mi][ni][r] + bvv);
        *(bf16x4*)(Vt + (((size_t)(bb * 16 + hh) * 64 + d) << 10) + s0) = ov;
      }
    }
  }
}

// ---------------- output projection GEMM (fp32 out, 2-phase dbuf) ----------------
__global__ __launch_bounds__(256, 2)
void gemm_fc(const __bf16* __restrict__ A, const __bf16* __restrict__ W,
             const float* __restrict__ bias, float* __restrict__ C) {
  __shared__ __bf16 As[2][128 * 64];
  __shared__ __bf16 Bs[2][128 * 64];
  const int bm = blockIdx.x, bn = blockIdx.y;
  const int tid = threadIdx.x, wave = tid >> 6, lane = tid & 63;
  const int wr = wave >> 1, wc = wave & 1;
  const int rl = lane >> 3, c8 = lane & 7;
  f32x4 acc[4][4] = {};

#define FC_STAGE(bb, kt)                                                              \
  {                                                                                   \
    _Pragma("unroll")                                                                 \
    for (int i = 0; i < 4; ++i) {                                                     \
      int row = wave * 32 + i * 8 + rl;                                               \
      int sw = (c8 ^ (row & 7)) << 3;                                                 \
      gload_lds16(A + (size_t)(bm * 128 + row) * 1024 + (kt) * 64 + sw,               \
                  &As[bb][(wave * 32 + i * 8) * 64]);                                 \
      gload_lds16(W + (size_t)(bn * 128 + row) * 1024 + (kt) * 64 + sw,               \
                  &Bs[bb][(wave * 32 + i * 8) * 64]);                                 \
    }                                                                                 \
  }

  FC_STAGE(0, 0);
  __syncthreads();
  int buf = 0;
  for (int kt = 0; kt < 16; ++kt) {
    if (kt < 15) FC_STAGE(buf ^ 1, kt + 1);
#pragma unroll
    for (int k32 = 0; k32 < 2; ++k32) {
      bf16x8 af[4], bfr[4];
#pragma unroll
      for (int mi = 0; mi < 4; ++mi) {
        int row = wr * 64 + mi * 16 + (lane & 15);
        af[mi] = *(const bf16x8*)(&As[buf][row * 64 + (((k32 * 4 + (lane >> 4)) ^ (row & 7)) << 3)]);
      }
#pragma unroll
      for (int ni = 0; ni < 4; ++ni) {
        int row = wc * 64 + ni * 16 + (lane & 15);
        bfr[ni] = *(const bf16x8*)(&Bs[buf][row * 64 + (((k32 * 4 + (lane >> 4)) ^ (row & 7)) << 3)]);
      }
#pragma unroll
      for (int mi = 0; mi < 4; ++mi)
#pragma unroll
        for (int ni = 0; ni < 4; ++ni)
          acc[mi][ni] = MFMA16(af[mi], bfr[ni], acc[mi][ni]);
    }
    __syncthreads();
    buf ^= 1;
  }
  const int r0 = (lane >> 4) * 4, cl = lane & 15;
#pragma unroll
  for (int ni = 0; ni < 4; ++ni) {
    int col = bn * 128 + wc * 64 + ni * 16 + cl;
    float bvv = bias[col];
#pragma unroll
    for (int mi = 0; mi < 4; ++mi) {
      int rowb = bm * 128 + wr * 64 + mi * 16 + r0;
#pragma unroll
      for (int r = 0; r < 4; ++r)
        C[(size_t)(rowb + r) * 1024 + col] = acc[mi][ni][r] + bvv;
    }
  }
}

// ---------------- fused attention: LDS-staged K/V + in-register P ----------------
// Swapped QK^T (A=K,B=Q) -> S^T col=q=lane&31, row=k=crow(r,hi); P in registers;
// hi/lo exchange via v_permlane32_swap_b32 (2 per PV frag); denominator via
// ones-MFMA (exactly consistent with bf16 numerator); mask bits via sbfe.
__global__ __launch_bounds__(256)
void attn32(const __bf16* __restrict__ Qp, const __bf16* __restrict__ Kp,
            const __bf16* __restrict__ Vt, const unsigned int* __restrict__ mp,
            __bf16* __restrict__ O) {
  __shared__ __bf16 Ks[2][64 * 64];   // [kv-local][d] granule-swizzled by row&7
  __shared__ __bf16 Vs[2][64 * 64];   // [d][kv-local] granule-swizzled by row&7
  const int tid = threadIdx.x, wave = tid >> 6, lane = tid & 63;
  const int lo5 = lane & 31, hi = lane >> 5;
  const int bx = blockIdx.x;
  const int qt = bx & 7, h = (bx >> 3) & 15, b = bx >> 7;
  const int qrow = qt * 128 + wave * 32 + lo5;

  const int srow = tid >> 3;
  const int sgx = ((tid & 7) ^ (srow & 7)) << 3;

#define ATTN_STAGE(bb, kt)                                                            \
  {                                                                                   \
    _Pragma("unroll")                                                                 \
    for (int i = 0; i < 2; ++i) {                                                     \
      gload_lds16(Kp + (size_t)(b * 1024 + (kt) * 64 + i * 32 + srow) * 1024          \
                     + h * 64 + sgx,                                                  \
                  &Ks[bb][i * 2048 + wave * 512]);                                    \
      gload_lds16(Vt + (size_t)((b * 16 + h) * 64 + i * 32 + srow) * 1024             \
                     + (kt) * 64 + sgx,                                               \
                  &Vs[bb][i * 2048 + wave * 512]);                                    \
    }                                                                                 \
  }

  // Q fragments (Q pre-scaled by 1/8*log2e in gemm_qkv)
  bf16x8 qf[4];
  const __bf16* qb = Qp + ((size_t)(b * 1024 + qrow)) * 1024 + h * 64 + hi * 8;
#pragma unroll
  for (int m = 0; m < 4; ++m) qf[m] = *(const bf16x8*)(qb + m * 16);

  bf16x8 onesf;
#pragma unroll
  for (int i = 0; i < 8; ++i) onesf[i] = (__bf16)1.0f;

  f32x16 oacc0 = {}, oacc1 = {}, oaccD = {};
  const uint2* mrow = ((const uint2*)mp) + ((size_t)(b * 1024 + qrow)) * 16;
  const int x = lo5 & 7;

  ATTN_STAGE(0, 0);
  uint2 mwc = mrow[0];
  __syncthreads();
  int buf = 0;
  for (int kt = 0; kt < 16; ++kt) {
    if (kt < 15) ATTN_STAGE(buf ^ 1, kt + 1);
    uint2 mwn = mwc;
    if (kt < 15) mwn = mrow[kt + 1];   // prefetch next mask words
#pragma unroll
    for (int sub = 0; sub < 2; ++sub) {
      // S^T subtile: rows k = kt*64 + sub*32 + crow, cols q
      f32x16 s = {};
#pragma unroll
      for (int m = 0; m < 4; ++m) {
        bf16x8 kf = *(const bf16x8*)(&Ks[buf][(sub * 32 + lo5) * 64 + (((2 * m + hi) ^ x) << 3)]);
        s = MFMA32(kf, qf[m], s);
      }
      // keep-mask word: bit==1 in nw means NOT masked
      unsigned w32 = sub == 0 ? mwc.x : mwc.y;
      unsigned nw = ~(w32 >> (hi * 4));
      float p[16];
#pragma unroll
      for (int r = 0; r < 16; ++r) {
        float e = __builtin_amdgcn_exp2f(s[r]);
        unsigned keep = (unsigned)__builtin_amdgcn_sbfe((int)nw, (unsigned)((r & 3) + 8 * (r >> 2)), 1u);
        p[r] = __uint_as_float(__float_as_uint(e) & keep);
      }
      unsigned own[8];
#pragma unroll
      for (int u = 0; u < 4; ++u) {
        own[2 * u]     = pack2(p[4 * u],     p[4 * u + 1]);
        own[2 * u + 1] = pack2(p[4 * u + 2], p[4 * u + 3]);
      }
#pragma unroll
      for (int sf = 0; sf < 2; ++sf) {
        unsigned a0 = own[4 * sf + 0], b0 = own[4 * sf + 2];
        unsigned a1 = own[4 * sf + 1], b1 = own[4 * sf + 3];
        asm volatile("v_permlane32_swap_b32 %0, %1" : "+v"(a0), "+v"(b0));
        asm volatile("v_permlane32_swap_b32 %0, %1" : "+v"(a1), "+v"(b1));
        bf16x8 pa = mkfrag(a0, a1, b0, b1);
        int g = ((sub * 4 + sf * 2 + hi) ^ x) << 3;
        bf16x8 vf0 = *(const bf16x8*)(&Vs[buf][lo5 * 64 + g]);
        bf16x8 vf1 = *(const bf16x8*)(&Vs[buf][(lo5 + 32) * 64 + g]);
        oacc0 = MFMA32(pa, vf0, oacc0);
        oacc1 = MFMA32(pa, vf1, oacc1);
        oaccD = MFMA32(pa, onesf, oaccD);
      }
    }
    __syncthreads();
    buf ^= 1;
    mwc = mwn;
  }

  const size_t orow0 = (size_t)(b * 1024 + qt * 128 + wave * 32);
#pragma unroll
  for (int r = 0; r < 16; ++r) {
    int cr = (r & 3) + 8 * (r >> 2) + 4 * hi;
    float iv = __builtin_amdgcn_rcpf(oaccD[r]);
    __bf16* op = O + (orow0 + cr) * 1024 + h * 64 + lo5;
    op[0]  = (__bf16)(oacc0[r] * iv);
    op[32] = (__bf16)(oacc1[r] * iv);
  }
}

// ---------------- launch ----------------
extern "C" void kernel_launch(void* const* d_in, const int* in_sizes, int n_in,
                              void* d_out, int out_size, void* d_ws, size_t ws_size,
                              hipStream_t stream) {
  const float* query = (const float*)d_in[0];
  const float* key   = (const float*)d_in[1];
  const float* value = (const float*)d_in[2];
  const void*  mask  = d_in[3];
  const float* wq_w  = (const float*)d_in[4];
  const float* wq_b  = (const float*)d_in[5];
  const float* wk_w  = (const float*)d_in[6];
  const float* wk_b  = (const float*)d_in[7];
  const float* wv_w  = (const float*)d_in[8];
  const float* wv_b  = (const float*)d_in[9];
  const float* fc_w  = (const float*)d_in[10];
  const float* fc_b  = (const float*)d_in[11];

  char* ws = (char*)d_ws;
  __bf16* qb  = (__bf16*)ws;
  __bf16* kb  = qb  + 4194304;
  __bf16* vb  = kb  + 4194304;
  __bf16* wqb = vb  + 4194304;
  __bf16* wkb = wqb + 1048576;
  __bf16* wvb = wkb + 1048576;
  __bf16* fcb = wvb + 1048576;
  __bf16* Qp  = fcb + 1048576;
  __bf16* Kp  = Qp  + 4194304;
  __bf16* Vt  = Kp  + 4194304;        // V proj, per-head transposed [B,H,64,S]
  __bf16* Ob  = Vt  + 4194304;
  unsigned int* mpk = (unsigned int*)(Ob + 4194304);
  int* flag = (int*)(mpk + 131072);

  detect_mask<<<1, 256, 0, stream>>>((const unsigned char*)mask, flag);
  pack_mask<<<16384, 256, 0, stream>>>(mask, flag, mpk);
  cvt_all<<<16384, 256, 0, stream>>>(query, key, value, wq_w, wk_w, wv_w, fc_w,
                                     qb, kb, vb, wqb, wkb, wvb, fcb);
  dim3 g1(32, 24);
  gemm_qkv<<<g1, 256, 0, stream>>>(qb, kb, vb, wqb, wkb, wvb, wq_b, wk_b, wv_b, Qp, Kp, Vt);
  attn32<<<512, 256, 0, stream>>>(Qp, Kp, Vt, mpk, Ob);
  dim3 g2(32, 8);
  gemm_fc<<<g2, 256, 0, stream>>>(Ob, fcb, fc_b, (float*)d_out);
}